// Round 7
// baseline (2705.038 us; speedup 1.0000x reference)
//
#include <hip/hip_runtime.h>

// Problem constants
#define T_STEPS 100
#define BATCH   512
#define D0      700
#define D1      512
#define D2      20
#define M_ROWS  (T_STEPS * BATCH)   // 51200

// Output layout (floats): [s2 (T*B*20) | s1 (T*B*512) | s2 copy (T*B*20)]
#define OFF_S2A 0
#define OFF_S1  (T_STEPS * BATCH * D2)                    // 1,024,000
#define OFF_S2B (OFF_S1 + T_STEPS * BATCH * D1)           // 27,238,400

__device__ __constant__ const float kALPHA = 0.8f;
__device__ __constant__ const float kBETA  = 0.9f;
__device__ __constant__ const float kTHR   = 1.0f;

// ---------------------------------------------------------------------------
// W-transpose: Wt[k][o] = W1[o][k].  Wt lives in the s2b output slot (4 MB,
// used as scratch; scan2 overwrites it at the end of the launch sequence).
// ---------------------------------------------------------------------------
__global__ __launch_bounds__(256)
void wt_kernel(const float* __restrict__ W, float* __restrict__ Wt) {
    __shared__ float t[32][33];
    const int k0 = blockIdx.x * 32;   // 0..21 (704, guarded)
    const int o0 = blockIdx.y * 32;   // 0..15
    const int tx = threadIdx.x, ty = threadIdx.y;   // 32 x 8
#pragma unroll
    for (int s = 0; s < 32; s += 8) {
        const int k = k0 + tx;
        t[ty + s][tx] = (k < D0) ? W[(size_t)(o0 + ty + s) * D0 + k] : 0.f;
    }
    __syncthreads();
#pragma unroll
    for (int s = 0; s < 32; s += 8) {
        const int k = k0 + ty + s;
        if (k < D0) Wt[(size_t)k * D1 + o0 + tx] = t[tx][ty + s];
    }
}

// ---------------------------------------------------------------------------
// GEMM1: C[M,512] = A[M,700] * W1^T, via Wt[700][512] (k-major).
// 128x128 block tile, 256 threads, 8x8 microtile — but BARRIER-FREE:
//  - Each wave w computes rows 32w..32w+31 and stages ONLY those A rows into
//    a private per-wave LDS slab [32][36] (double-buffered, 2x4.6KB/wave).
//    No wave reads another wave's slab => no __syncthreads anywhere; all
//    ordering is wave-local vmcnt/lgkmcnt (compiler-inserted). Waves drift
//    freely -> no barrier convoy; latency hidden by 16 unsynced waves/CU.
//  - B-fragments stream from Wt via L1/L2 (2 float4 per k per thread,
//    16-segment coalesced + 4-lane broadcast; W col-panel is L2-resident,
//    k-tile slice is L1-resident).
//  - Slab layout: row stride 36 floats (144B, 16B-aligned for b128 ops),
//    chunk c of row r stored at position c ^ (r>>3) (low 2 bits).
//    Staging b128 writes: uniform depth-8 over all bank groups (free).
//    Compute b64 reads: 4 distinct bank-slots x 16-lane broadcast (free).
//  - fmaf chain ascending-k, identical order to R2 -> bitwise-identical C.
//  - launch_bounds(256,4): force VGPR<=128 (4 waves/SIMD).
// Grid swizzle kept (FETCH 287->102MB): XCD x = id%8 owns row-panels
// [50x,50x+50), col fastest.
// ---------------------------------------------------------------------------
constexpr int BM = 128, BN = 128, BK = 32;
constexpr int SLAB = 32 * 36;            // floats per slab buffer

template <int NP>
__device__ __forceinline__ void compute_tile(const float* __restrict__ slab,
                                             const float* __restrict__ wbase,
                                             int typ, float acc[8][8]) {
#pragma unroll
    for (int p = 0; p < NP; ++p) {                 // 2 k's per step
        const int cpos = (((p >> 1) ^ typ) << 2) + ((p & 1) << 1);
        float2 av[8];
#pragma unroll
        for (int i = 0; i < 8; ++i)
            av[i] = *(const float2*)&slab[(typ * 8 + i) * 36 + cpos];
        const float4 w00 = *(const float4*)(wbase + (size_t)(2 * p) * D1);
        const float4 w01 = *(const float4*)(wbase + (size_t)(2 * p) * D1 + 4);
        const float4 w10 = *(const float4*)(wbase + (size_t)(2 * p + 1) * D1);
        const float4 w11 = *(const float4*)(wbase + (size_t)(2 * p + 1) * D1 + 4);
        const float b0[8] = {w00.x, w00.y, w00.z, w00.w, w01.x, w01.y, w01.z, w01.w};
        const float b1[8] = {w10.x, w10.y, w10.z, w10.w, w11.x, w11.y, w11.z, w11.w};
        // k = 2p
#pragma unroll
        for (int i = 0; i < 8; ++i)
#pragma unroll
            for (int j = 0; j < 8; ++j)
                acc[i][j] = fmaf(av[i].x, b0[j], acc[i][j]);
        // k = 2p+1
#pragma unroll
        for (int i = 0; i < 8; ++i)
#pragma unroll
            for (int j = 0; j < 8; ++j)
                acc[i][j] = fmaf(av[i].y, b1[j], acc[i][j]);
    }
}

__global__ __launch_bounds__(256, 4)
void gemm1_kernel(const float* __restrict__ A, const float* __restrict__ Wt,
                  float* __restrict__ C) {
    __shared__ float As[4][2][SLAB];     // 4 waves x dbuf x 4608B = 36864 B

    // XCD-chunked remap: 1600 blocks, 8 XCDs, 200 each; col fastest.
    const int d     = blockIdx.x;
    const int xcd   = d & 7;
    const int local = d >> 3;            // 0..199
    const int brow  = xcd * 50 + (local >> 2);
    const int bcol  = local & 3;

    const int tid  = threadIdx.x;
    const int row0 = brow * BM;
    const int col0 = bcol * BN;
    const int wave = tid >> 6;
    const int lane = tid & 63;
    const int tx   = tid & 15;           // 0..15 (N)
    const int ty   = tid >> 4;           // 0..15 (M), wave w has ty in 4w..4w+3
    const int typ  = ty & 3;             // within-wave row group

    // staging coords: lane covers local row sr, chunks 4h..4h+3
    const int sr = lane & 31;
    const int sh = lane >> 5;
    const int sa = sr >> 3;              // row's swizzle key (0..3)
    const float* arow = A + (size_t)(row0 + wave * 32 + sr) * D0;
    const float* wcol = Wt + col0 + tx * 8;

    float acc[8][8];
#pragma unroll
    for (int i = 0; i < 8; ++i)
#pragma unroll
        for (int j = 0; j < 8; ++j) acc[i][j] = 0.f;

    float4 g[4];
    auto ALOAD = [&](int kt) {
#pragma unroll
        for (int q = 0; q < 4; ++q) {
            int kk = kt * BK + sh * 16 + 4 * q;
            kk = kk > 696 ? 696 : kk;            // last-tile clamp (unused data)
            g[q] = *(const float4*)(arow + kk);
        }
    };
    auto AWRITE = [&](float* slab) {
#pragma unroll
        for (int q = 0; q < 4; ++q)
            *(float4*)&slab[sr * 36 + ((sh * 4 + (q ^ sa)) << 2)] = g[q];
    };

    float* slab0 = &As[wave][0][0];
    float* slab1 = &As[wave][1][0];

    // prologue: stage tile 0 into slab0
    ALOAD(0);
    AWRITE(slab0);

    const int NT = 22;   // 21 full 32-k tiles + one 28-k tile
    int cur = 0;
    for (int kt = 0; kt < NT; ++kt) {
        if (kt + 1 < NT) ALOAD(kt + 1);          // issue early; covered by FMAs
        const float* slab = cur ? slab1 : slab0;
        const float* wb   = wcol + (size_t)(kt * BK) * D1;
        if (kt + 1 < NT) compute_tile<16>(slab, wb, typ, acc);
        else             compute_tile<14>(slab, wb, typ, acc);   // 28 k
        if (kt + 1 < NT) { AWRITE(cur ? slab0 : slab1); cur ^= 1; }
    }

#pragma unroll
    for (int i = 0; i < 8; ++i) {
        float* cp = C + (size_t)(row0 + ty * 8 + i) * D1 + col0 + tx * 8;
        float4 v0 = make_float4(acc[i][0], acc[i][1], acc[i][2], acc[i][3]);
        float4 v1 = make_float4(acc[i][4], acc[i][5], acc[i][6], acc[i][7]);
        *(float4*)(cp + 0) = v0;
        *(float4*)(cp + 4) = v1;
    }
}

// ---------------------------------------------------------------------------
// Scan 1: in-place over pre1 buffer [T, B*512]; each thread owns one neuron.
// ---------------------------------------------------------------------------
__global__ __launch_bounds__(256)
void scan1_kernel(float* __restrict__ buf) {
#pragma clang fp contract(off)
    const int idx = blockIdx.x * blockDim.x + threadIdx.x;  // 0 .. 262143
    const int stride = BATCH * D1;
    float syn = 0.f, mem = 0.f;
    float* p = buf + idx;
    for (int t = 0; t < T_STEPS; ++t) {
        const float pre = p[(size_t)t * stride];
        float a = kALPHA * syn;
        syn = a + pre;
        const float reset = (mem > kTHR) ? 1.f : 0.f;
        float bm = kBETA * mem;
        mem = (bm + syn) * (1.f - reset);
        p[(size_t)t * stride] = (mem > kTHR) ? 1.f : 0.f;
    }
}

// ---------------------------------------------------------------------------
// GEMM2: C[M,20] = S1[M,512] * W2[20,512]^T.  W2 staged in LDS (40 KB).
// 256 threads = 64 rows x 4 k-quarters; shuffle-reduce across the 4.
// ---------------------------------------------------------------------------
__global__ __launch_bounds__(256)
void gemm2_kernel(const float* __restrict__ S1, const float* __restrict__ W2,
                  float* __restrict__ C) {
    __shared__ float Wsh[D2 * D1];  // 10240 floats = 40 KB
    for (int i = threadIdx.x; i < (D2 * D1) / 4; i += 256)
        ((float4*)Wsh)[i] = ((const float4*)W2)[i];
    __syncthreads();

    const int r  = threadIdx.x >> 2;   // 0..63
    const int kq = threadIdx.x & 3;    // k quarter (128 each)
    const int m  = blockIdx.x * 64 + r;

    const float4* src = (const float4*)(S1 + (size_t)m * D1 + kq * 128);
    float acc[D2];
#pragma unroll
    for (int o = 0; o < D2; ++o) acc[o] = 0.f;

    for (int j = 0; j < 32; ++j) {
        const float4 v = src[j];
        const float* wbase = Wsh + kq * 128 + j * 4;
#pragma unroll
        for (int o = 0; o < D2; ++o) {
            const float4 w = *(const float4*)(wbase + o * D1);
            acc[o] += v.x * w.x + v.y * w.y + v.z * w.z + v.w * w.w;
        }
    }
    // reduce over the 4 k-quarters (consecutive lanes)
#pragma unroll
    for (int o = 0; o < D2; ++o) {
        acc[o] += __shfl_xor(acc[o], 1);
        acc[o] += __shfl_xor(acc[o], 2);
    }
    if (kq == 0) {
        float* cp = C + (size_t)m * D2;
#pragma unroll
        for (int o = 0; o < D2; o += 4)
            *(float4*)(cp + o) = make_float4(acc[o], acc[o + 1], acc[o + 2], acc[o + 3]);
    }
}

// ---------------------------------------------------------------------------
// Scan 2: in-place over pre2 [T, B*20]; also writes the duplicate s2 slot.
// ---------------------------------------------------------------------------
__global__ __launch_bounds__(256)
void scan2_kernel(float* __restrict__ buf, float* __restrict__ dup) {
#pragma clang fp contract(off)
    const int idx = blockIdx.x * blockDim.x + threadIdx.x;  // 0 .. 10239
    const int stride = BATCH * D2;
    float syn = 0.f, mem = 0.f;
    for (int t = 0; t < T_STEPS; ++t) {
        const size_t off = (size_t)t * stride + idx;
        const float pre = buf[off];
        float a = kALPHA * syn;
        syn = a + pre;
        const float reset = (mem > kTHR) ? 1.f : 0.f;
        float bm = kBETA * mem;
        mem = (bm + syn) * (1.f - reset);
        const float s = (mem > kTHR) ? 1.f : 0.f;
        buf[off] = s;
        dup[off] = s;
    }
}

// ---------------------------------------------------------------------------
extern "C" void kernel_launch(void* const* d_in, const int* in_sizes, int n_in,
                              void* d_out, int out_size, void* d_ws, size_t ws_size,
                              hipStream_t stream) {
    const float* x  = (const float*)d_in[0];   // [100, 512, 700]
    const float* W1 = (const float*)d_in[1];   // [512, 700]
    const float* W2 = (const float*)d_in[2];   // [20, 512]
    float* out = (float*)d_out;

    float* s2a = out + OFF_S2A;   // [T,B,20]  (pre2 then s2)
    float* s1  = out + OFF_S1;    // [T,B,512] (pre1 then s1)
    float* s2b = out + OFF_S2B;   // [T,B,20]  scratch Wt, then duplicate s2

    // 0) Wt[700][512] = W1^T  (into s2b slot, overwritten later by scan2)
    wt_kernel<<<dim3(22, 16), dim3(32, 8), 0, stream>>>(W1, s2b);

    // 1) pre1 = x @ W1^T  -> s1 slot  (barrier-free per-wave pipeline)
    gemm1_kernel<<<(M_ROWS / BM) * (D1 / BN), 256, 0, stream>>>(x, s2b, s1);

    // 2) scan layer 1 in place (pre1 -> spikes)
    scan1_kernel<<<(BATCH * D1) / 256, 256, 0, stream>>>(s1);

    // 3) pre2 = s1 @ W2^T -> s2a slot
    gemm2_kernel<<<M_ROWS / 64, 256, 0, stream>>>(s1, W2, s2a);

    // 4) scan layer 2 in place + duplicate (overwrites Wt scratch)
    scan2_kernel<<<(BATCH * D2) / 256, 256, 0, stream>>>(s2a, s2b);
}

// Round 8
// 844.113 us; speedup vs baseline: 3.2046x; 3.2046x over previous
//
#include <hip/hip_runtime.h>

// Problem constants
#define T_STEPS 100
#define BATCH   512
#define D0      700
#define D1      512
#define D2      20
#define M_ROWS  (T_STEPS * BATCH)   // 51200

// Output layout (floats): [s2 (T*B*20) | s1 (T*B*512) | s2 copy (T*B*20)]
#define OFF_S2A 0
#define OFF_S1  (T_STEPS * BATCH * D2)                    // 1,024,000
#define OFF_S2B (OFF_S1 + T_STEPS * BATCH * D1)           // 27,238,400

__device__ __constant__ const float kALPHA = 0.8f;
__device__ __constant__ const float kBETA  = 0.9f;
__device__ __constant__ const float kTHR   = 1.0f;

// ---------------------------------------------------------------------------
// W-transpose: Wt[k][o] = W1[o][k].  Wt lives in the s2b output slot (4 MB
// scratch; scan2 fully overwrites it at the end).  Proven in R7 (absmax 0).
// ---------------------------------------------------------------------------
__global__ __launch_bounds__(256)
void wt_kernel(const float* __restrict__ W, float* __restrict__ Wt) {
    __shared__ float t[32][33];
    const int k0 = blockIdx.x * 32;   // 0..21 (704, guarded)
    const int o0 = blockIdx.y * 32;   // 0..15
    const int tx = threadIdx.x, ty = threadIdx.y;   // 32 x 8
#pragma unroll
    for (int s = 0; s < 32; s += 8) {
        const int k = k0 + tx;
        t[ty + s][tx] = (k < D0) ? W[(size_t)(o0 + ty + s) * D0 + k] : 0.f;
    }
    __syncthreads();
#pragma unroll
    for (int s = 0; s < 32; s += 8) {
        const int k = k0 + ty + s;
        if (k < D0) Wt[(size_t)k * D1 + o0 + tx] = t[tx][ty + s];
    }
}

// ---------------------------------------------------------------------------
// GEMM1: C[M,512] = A[M,700] * W1^T, via Wt[700][512] (k-major).
// SCALAR-BROADCAST STRUCTURE (attacks the measured LDS-return-bus wall:
// old 8x8 microtile = 2 FLOP/LDS-byte -> 128 B/cy demand vs ~85-112 B/cy).
//   - block = 128 rows x 128 cols, 256 threads, BK=32, 22 k-tiles.
//   - wave w owns cols [col0+32w, +32): W-slice address is WAVE-UNIFORM ->
//     compiler promotes to s_load (readfirstlane'd wave id + __restrict__
//     no-clobber); w-operand feeds v_fma's SGPR slot. Zero LDS for W.
//   - lane owns rows {row0+2*lane, +1}: a-pair from LDS, 8 B/lane/k for
//     64 FMA = 16 FLOP/LDS-byte -> LDS port ~13% utilized.
//   - LDS = A-tile only, k-major [32][128], 16 KB, single-buffered,
//     2 barriers/tile (R2's proven skeleton; R3/R5/R6/R7 cliffs avoided:
//     acc 64 + staging ~28 VGPR < 128).
//   - chunk-XOR swizzle g(k)=((k>>2)+(k&3))&7 on 16B chunks of each k-row:
//     staging b32 scatter = 2 lanes/bank (free, m136); b64 reads =
//     contiguous 512B permuted (conflict-free).
//   - fmaf chain ascending-k per output, same order as R1-R7 -> bitwise-
//     identical spikes (absmax 0.0 expected).
// Grid swizzle kept (FETCH 287->102 MB): XCD x = id%8 owns row-panels
// [50x,50x+50), col fastest.
// ---------------------------------------------------------------------------
constexpr int BM = 128, BN = 128, BK = 32;

template <int NK>
__device__ __forceinline__ void ctile(const float* __restrict__ Ast,
                                      const float* __restrict__ wr,
                                      int lane, float* __restrict__ acc) {
    const int cbase = lane >> 1;          // 16B chunk holding cols {2l,2l+1}
    const int soff  = (lane & 1) << 1;    // float slot within chunk
#pragma unroll
    for (int kk = 0; kk < NK; ++kk) {
        const int g = ((kk >> 2) + (kk & 3)) & 7;          // compile-time
        const float2 a = *(const float2*)&Ast[kk * BM + ((cbase ^ g) << 2) + soff];
        const float* wp = wr + kk * D1;                    // wave-uniform
#pragma unroll
        for (int j = 0; j < 32; j += 4) {
            const float4 w = *(const float4*)(wp + j);     // -> s_load_dwordx4
            acc[j + 0]      = fmaf(a.x, w.x, acc[j + 0]);
            acc[j + 1]      = fmaf(a.x, w.y, acc[j + 1]);
            acc[j + 2]      = fmaf(a.x, w.z, acc[j + 2]);
            acc[j + 3]      = fmaf(a.x, w.w, acc[j + 3]);
            acc[32 + j + 0] = fmaf(a.y, w.x, acc[32 + j + 0]);
            acc[32 + j + 1] = fmaf(a.y, w.y, acc[32 + j + 1]);
            acc[32 + j + 2] = fmaf(a.y, w.z, acc[32 + j + 2]);
            acc[32 + j + 3] = fmaf(a.y, w.w, acc[32 + j + 3]);
        }
    }
}

__global__ __launch_bounds__(256)
void gemm1_kernel(const float* __restrict__ A, const float* __restrict__ Wt,
                  float* __restrict__ C) {
    __shared__ float Ast[BK * BM];       // 16 KB, k-major, chunk-swizzled

    // XCD-chunked remap: 1600 blocks, 8 XCDs, 200 each; col fastest.
    const int d     = blockIdx.x;
    const int xcd   = d & 7;
    const int local = d >> 3;            // 0..199
    const int brow  = xcd * 50 + (local >> 2);
    const int bcol  = local & 3;

    const int tid  = threadIdx.x;
    const int row0 = brow * BM;
    const int col0 = bcol * BN;
    const int lane = tid & 63;
    // wave id as an explicitly wave-uniform value -> W addresses scalarize
    const int wu   = __builtin_amdgcn_readfirstlane(tid >> 6);

    const float* wcol = Wt + col0 + wu * 32;

    float acc[64];
#pragma unroll
    for (int i = 0; i < 64; ++i) acc[i] = 0.f;

    for (int kt = 0; kt < 22; ++kt) {
        const int k0 = kt * BK;
        // stage A-tile: 128 rows x 32 k = 1024 float4; 4 per thread.
#pragma unroll
        for (int l = 0; l < 4; ++l) {
            const int f   = tid + (l << 8);     // 0..1023
            const int r   = f >> 3;             // A-row within tile
            const int gsw = f & 7;              // k-quad index = (k4)>>2
            const int k4  = gsw << 2;
            int gk = k0 + k4;
            if (gk > 696) gk = 696;             // last-tile clamp (unread data)
            const float4 v = *(const float4*)(A + (size_t)(row0 + r) * D0 + gk);
            const int rc = r >> 2, rs = r & 3;
            Ast[(k4 + 0) * BM + ((rc ^ ((gsw + 0) & 7)) << 2) + rs] = v.x;
            Ast[(k4 + 1) * BM + ((rc ^ ((gsw + 1) & 7)) << 2) + rs] = v.y;
            Ast[(k4 + 2) * BM + ((rc ^ ((gsw + 2) & 7)) << 2) + rs] = v.z;
            Ast[(k4 + 3) * BM + ((rc ^ ((gsw + 3) & 7)) << 2) + rs] = v.w;
        }
        __syncthreads();
        const float* wr = wcol + (size_t)k0 * D1;
        if (kt < 21) ctile<32>(Ast, wr, lane, acc);
        else         ctile<28>(Ast, wr, lane, acc);   // 700 = 21*32 + 28
        __syncthreads();
    }

    // C-write: lane's two rows x 32 cols, contiguous float4s.
    const int r0 = row0 + (lane << 1);
    float* c0 = C + (size_t)r0 * D1 + col0 + wu * 32;
    float* c1 = c0 + D1;
#pragma unroll
    for (int j = 0; j < 32; j += 4) {
        *(float4*)(c0 + j) = make_float4(acc[j], acc[j + 1], acc[j + 2], acc[j + 3]);
        *(float4*)(c1 + j) = make_float4(acc[32 + j], acc[33 + j], acc[34 + j], acc[35 + j]);
    }
}

// ---------------------------------------------------------------------------
// Scan 1: in-place over pre1 buffer [T, B*512]; each thread owns one neuron.
// ---------------------------------------------------------------------------
__global__ __launch_bounds__(256)
void scan1_kernel(float* __restrict__ buf) {
#pragma clang fp contract(off)
    const int idx = blockIdx.x * blockDim.x + threadIdx.x;  // 0 .. 262143
    const int stride = BATCH * D1;
    float syn = 0.f, mem = 0.f;
    float* p = buf + idx;
    for (int t = 0; t < T_STEPS; ++t) {
        const float pre = p[(size_t)t * stride];
        float a = kALPHA * syn;
        syn = a + pre;
        const float reset = (mem > kTHR) ? 1.f : 0.f;
        float bm = kBETA * mem;
        mem = (bm + syn) * (1.f - reset);
        p[(size_t)t * stride] = (mem > kTHR) ? 1.f : 0.f;
    }
}

// ---------------------------------------------------------------------------
// GEMM2: C[M,20] = S1[M,512] * W2[20,512]^T.  W2 staged in LDS (40 KB).
// 256 threads = 64 rows x 4 k-quarters; shuffle-reduce across the 4.
// ---------------------------------------------------------------------------
__global__ __launch_bounds__(256)
void gemm2_kernel(const float* __restrict__ S1, const float* __restrict__ W2,
                  float* __restrict__ C) {
    __shared__ float Wsh[D2 * D1];  // 10240 floats = 40 KB
    for (int i = threadIdx.x; i < (D2 * D1) / 4; i += 256)
        ((float4*)Wsh)[i] = ((const float4*)W2)[i];
    __syncthreads();

    const int r  = threadIdx.x >> 2;   // 0..63
    const int kq = threadIdx.x & 3;    // k quarter (128 each)
    const int m  = blockIdx.x * 64 + r;

    const float4* src = (const float4*)(S1 + (size_t)m * D1 + kq * 128);
    float acc[D2];
#pragma unroll
    for (int o = 0; o < D2; ++o) acc[o] = 0.f;

    for (int j = 0; j < 32; ++j) {
        const float4 v = src[j];
        const float* wbase = Wsh + kq * 128 + j * 4;
#pragma unroll
        for (int o = 0; o < D2; ++o) {
            const float4 w = *(const float4*)(wbase + o * D1);
            acc[o] += v.x * w.x + v.y * w.y + v.z * w.z + v.w * w.w;
        }
    }
    // reduce over the 4 k-quarters (consecutive lanes)
#pragma unroll
    for (int o = 0; o < D2; ++o) {
        acc[o] += __shfl_xor(acc[o], 1);
        acc[o] += __shfl_xor(acc[o], 2);
    }
    if (kq == 0) {
        float* cp = C + (size_t)m * D2;
#pragma unroll
        for (int o = 0; o < D2; o += 4)
            *(float4*)(cp + o) = make_float4(acc[o], acc[o + 1], acc[o + 2], acc[o + 3]);
    }
}

// ---------------------------------------------------------------------------
// Scan 2: in-place over pre2 [T, B*20]; also writes the duplicate s2 slot.
// ---------------------------------------------------------------------------
__global__ __launch_bounds__(256)
void scan2_kernel(float* __restrict__ buf, float* __restrict__ dup) {
#pragma clang fp contract(off)
    const int idx = blockIdx.x * blockDim.x + threadIdx.x;  // 0 .. 10239
    const int stride = BATCH * D2;
    float syn = 0.f, mem = 0.f;
    for (int t = 0; t < T_STEPS; ++t) {
        const size_t off = (size_t)t * stride + idx;
        const float pre = buf[off];
        float a = kALPHA * syn;
        syn = a + pre;
        const float reset = (mem > kTHR) ? 1.f : 0.f;
        float bm = kBETA * mem;
        mem = (bm + syn) * (1.f - reset);
        const float s = (mem > kTHR) ? 1.f : 0.f;
        buf[off] = s;
        dup[off] = s;
    }
}

// ---------------------------------------------------------------------------
extern "C" void kernel_launch(void* const* d_in, const int* in_sizes, int n_in,
                              void* d_out, int out_size, void* d_ws, size_t ws_size,
                              hipStream_t stream) {
    const float* x  = (const float*)d_in[0];   // [100, 512, 700]
    const float* W1 = (const float*)d_in[1];   // [512, 700]
    const float* W2 = (const float*)d_in[2];   // [20, 512]
    float* out = (float*)d_out;

    float* s2a = out + OFF_S2A;   // [T,B,20]  (pre2 then s2)
    float* s1  = out + OFF_S1;    // [T,B,512] (pre1 then s1)
    float* s2b = out + OFF_S2B;   // [T,B,20]  scratch Wt, then duplicate s2

    // 0) Wt[700][512] = W1^T  (into s2b slot, overwritten later by scan2)
    wt_kernel<<<dim3(22, 16), dim3(32, 8), 0, stream>>>(W1, s2b);

    // 1) pre1 = x @ W1^T  -> s1 slot  (scalar-broadcast W, LDS = A only)
    gemm1_kernel<<<(M_ROWS / BM) * (D1 / BN), 256, 0, stream>>>(x, s2b, s1);

    // 2) scan layer 1 in place (pre1 -> spikes)
    scan1_kernel<<<(BATCH * D1) / 256, 256, 0, stream>>>(s1);

    // 3) pre2 = s1 @ W2^T -> s2a slot
    gemm2_kernel<<<M_ROWS / 64, 256, 0, stream>>>(s1, W2, s2a);

    // 4) scan layer 2 in place + duplicate (overwrites Wt scratch)
    scan2_kernel<<<(BATCH * D2) / 256, 256, 0, stream>>>(s2a, s2b);
}

// Round 9
// 621.482 us; speedup vs baseline: 4.3526x; 1.3582x over previous
//
#include <hip/hip_runtime.h>

// Problem constants
#define T_STEPS 100
#define BATCH   512
#define D0      700
#define D1      512
#define D2      20
#define M_ROWS  (T_STEPS * BATCH)   // 51200

// Output layout (floats): [s2 (T*B*20) | s1 (T*B*512) | s2 copy (T*B*20)]
#define OFF_S2A 0
#define OFF_S1  (T_STEPS * BATCH * D2)                    // 1,024,000
#define OFF_S2B (OFF_S1 + T_STEPS * BATCH * D1)           // 27,238,400

__device__ __constant__ const float kALPHA = 0.8f;
__device__ __constant__ const float kBETA  = 0.9f;
__device__ __constant__ const float kTHR   = 1.0f;

// ---------------------------------------------------------------------------
// GEMM1: C[M,512] = A[M,700] * W1[512,700]^T   (both row-major, K contiguous)
// R2/R4 skeleton (128x128 tile, BK=32, 256 thr, 8x8 microtile, single 32KB
// buffer, 2 barriers/tile, XCD swizzle) with the staging path rebuilt:
//   - global_load_lds staging: 8 instrs/wave/tile, ZERO staging VGPRs, no
//     b32 scatter (R2 spent ~16 writes + ~6 VALU ops each per thread/tile).
//   - LDS tiles row-major [row][8 chunks x 4 floats]; gll writes linear
//     (lane l of instr s -> row s*8+(l>>3), chunk l&7).
//   - Source-side XOR swizzle (m173 pattern; LDS stays linear): dest chunk
//     cl holds source k-chunk cl ^ (s&7), s = row>>3. Lane's 16B source
//     stays contiguous (legal for gll).
//   - Reads: ds_read_b128 covering 4 k. A-frag: per (i,kc) instr, 4 ty ->
//     4 distinct bank-quads (conflict-free). B-frag: 16 tx -> 8 quads x
//     2 addrs (2-way = free, m136).
//   - fmaf chain ascending-k per output element, same order as R1-R8 ->
//     bitwise-identical spikes.
//   - K edge: 700 = 21*32 + 28; last tile stages chunks clamped to byte
//     offset 2784 (in-row), compute uses 7 chunks (28 k).
// ---------------------------------------------------------------------------
constexpr int BM = 128, BN = 128, BK = 32;

template <int NCH>
__device__ __forceinline__ void ctile(const float* __restrict__ As,
                                      const float* __restrict__ Ws,
                                      int tx, int ty, float acc[8][8]) {
    const int ka = ty & 7, kb = tx & 7;
#pragma unroll
    for (int kc = 0; kc < NCH; ++kc) {          // 4 k's per chunk
        float4 av[8];
#pragma unroll
        for (int i = 0; i < 8; ++i)
            av[i] = *(const float4*)&As[(ty * 8 + i) * 32 + ((kc ^ ka) << 2)];
#pragma unroll
        for (int j = 0; j < 8; ++j) {
            const float4 b = *(const float4*)&Ws[(tx * 8 + j) * 32 + ((kc ^ kb) << 2)];
#pragma unroll
            for (int i = 0; i < 8; ++i) {       // ascending k: x,y,z,w
                acc[i][j] = fmaf(av[i].x, b.x, acc[i][j]);
                acc[i][j] = fmaf(av[i].y, b.y, acc[i][j]);
                acc[i][j] = fmaf(av[i].z, b.z, acc[i][j]);
                acc[i][j] = fmaf(av[i].w, b.w, acc[i][j]);
            }
        }
    }
}

__global__ __launch_bounds__(256)
void gemm1_kernel(const float* __restrict__ A, const float* __restrict__ W,
                  float* __restrict__ C) {
    __shared__ float As[BM * BK];   // 16 KB, [row][8x4], source-swizzled
    __shared__ float Ws[BN * BK];   // 16 KB

    // XCD-chunked remap: 1600 blocks, 8 XCDs, 200 each; col fastest.
    const int d     = blockIdx.x;
    const int xcd   = d & 7;
    const int local = d >> 3;            // 0..199
    const int brow  = xcd * 50 + (local >> 2);
    const int bcol  = local & 3;

    const int tid  = threadIdx.x;
    const int row0 = brow * BM;
    const int col0 = bcol * BN;
    const int wave = tid >> 6;
    const int lane = tid & 63;
    const int tx   = tid & 15;
    const int ty   = tid >> 4;

    float acc[8][8];
#pragma unroll
    for (int i = 0; i < 8; ++i)
#pragma unroll
        for (int j = 0; j < 8; ++j) acc[i][j] = 0.f;

    // ---- gll staging of tile kt: wave w covers row-groups s = 4w..4w+3 ----
    auto STAGE = [&](int kt) {
        const int kb0 = kt * 128;                    // byte offset of k0
#pragma unroll
        for (int q = 0; q < 4; ++q) {
            const int s = wave * 4 + q;              // row-group 0..15
            const int r = s * 8 + (lane >> 3);       // tile row of this lane
            int koff = kb0 + (((lane & 7) ^ (s & 7)) << 4);
            if (koff > 2784) koff = 2784;            // last-tile clamp (in-row)
            const char* ga = (const char*)A + (size_t)(row0 + r) * 2800 + koff;
            const char* gw = (const char*)W + (size_t)(col0 + r) * 2800 + koff;
            __builtin_amdgcn_global_load_lds(
                (const __attribute__((address_space(1))) void*)ga,
                (__attribute__((address_space(3))) void*)(As + s * 256), 16, 0, 0);
            __builtin_amdgcn_global_load_lds(
                (const __attribute__((address_space(1))) void*)gw,
                (__attribute__((address_space(3))) void*)(Ws + s * 256), 16, 0, 0);
        }
    };

    STAGE(0);
    __syncthreads();                     // drains vmcnt -> tile 0 ready

    for (int kt = 0; kt < 22; ++kt) {
        if (kt < 21) ctile<8>(As, Ws, tx, ty, acc);
        else         ctile<7>(As, Ws, tx, ty, acc);   // 28 k
        if (kt < 21) {
            __syncthreads();             // all waves done reading buffer
            STAGE(kt + 1);
            __syncthreads();             // drain vmcnt -> next tile ready
        }
    }

#pragma unroll
    for (int i = 0; i < 8; ++i) {
        float* cp = C + (size_t)(row0 + ty * 8 + i) * D1 + col0 + tx * 8;
        float4 v0 = make_float4(acc[i][0], acc[i][1], acc[i][2], acc[i][3]);
        float4 v1 = make_float4(acc[i][4], acc[i][5], acc[i][6], acc[i][7]);
        *(float4*)(cp + 0) = v0;
        *(float4*)(cp + 4) = v1;
    }
}

// ---------------------------------------------------------------------------
// Scan 1: in-place over pre1 buffer [T, B*512]; each thread owns one neuron.
// ---------------------------------------------------------------------------
__global__ __launch_bounds__(256)
void scan1_kernel(float* __restrict__ buf) {
#pragma clang fp contract(off)
    const int idx = blockIdx.x * blockDim.x + threadIdx.x;  // 0 .. 262143
    const int stride = BATCH * D1;
    float syn = 0.f, mem = 0.f;
    float* p = buf + idx;
    for (int t = 0; t < T_STEPS; ++t) {
        const float pre = p[(size_t)t * stride];
        float a = kALPHA * syn;
        syn = a + pre;
        const float reset = (mem > kTHR) ? 1.f : 0.f;
        float bm = kBETA * mem;
        mem = (bm + syn) * (1.f - reset);
        p[(size_t)t * stride] = (mem > kTHR) ? 1.f : 0.f;
    }
}

// ---------------------------------------------------------------------------
// GEMM2: C[M,20] = S1[M,512] * W2[20,512]^T.  W2 staged in LDS (40 KB).
// 256 threads = 64 rows x 4 k-quarters; shuffle-reduce across the 4.
// ---------------------------------------------------------------------------
__global__ __launch_bounds__(256)
void gemm2_kernel(const float* __restrict__ S1, const float* __restrict__ W2,
                  float* __restrict__ C) {
    __shared__ float Wsh[D2 * D1];  // 10240 floats = 40 KB
    for (int i = threadIdx.x; i < (D2 * D1) / 4; i += 256)
        ((float4*)Wsh)[i] = ((const float4*)W2)[i];
    __syncthreads();

    const int r  = threadIdx.x >> 2;   // 0..63
    const int kq = threadIdx.x & 3;    // k quarter (128 each)
    const int m  = blockIdx.x * 64 + r;

    const float4* src = (const float4*)(S1 + (size_t)m * D1 + kq * 128);
    float acc[D2];
#pragma unroll
    for (int o = 0; o < D2; ++o) acc[o] = 0.f;

    for (int j = 0; j < 32; ++j) {
        const float4 v = src[j];
        const float* wbase = Wsh + kq * 128 + j * 4;
#pragma unroll
        for (int o = 0; o < D2; ++o) {
            const float4 w = *(const float4*)(wbase + o * D1);
            acc[o] += v.x * w.x + v.y * w.y + v.z * w.z + v.w * w.w;
        }
    }
    // reduce over the 4 k-quarters (consecutive lanes)
#pragma unroll
    for (int o = 0; o < D2; ++o) {
        acc[o] += __shfl_xor(acc[o], 1);
        acc[o] += __shfl_xor(acc[o], 2);
    }
    if (kq == 0) {
        float* cp = C + (size_t)m * D2;
#pragma unroll
        for (int o = 0; o < D2; o += 4)
            *(float4*)(cp + o) = make_float4(acc[o], acc[o + 1], acc[o + 2], acc[o + 3]);
    }
}

// ---------------------------------------------------------------------------
// Scan 2: in-place over pre2 [T, B*20]; also writes the duplicate s2 slot.
// ---------------------------------------------------------------------------
__global__ __launch_bounds__(256)
void scan2_kernel(float* __restrict__ buf, float* __restrict__ dup) {
#pragma clang fp contract(off)
    const int idx = blockIdx.x * blockDim.x + threadIdx.x;  // 0 .. 10239
    const int stride = BATCH * D2;
    float syn = 0.f, mem = 0.f;
    for (int t = 0; t < T_STEPS; ++t) {
        const size_t off = (size_t)t * stride + idx;
        const float pre = buf[off];
        float a = kALPHA * syn;
        syn = a + pre;
        const float reset = (mem > kTHR) ? 1.f : 0.f;
        float bm = kBETA * mem;
        mem = (bm + syn) * (1.f - reset);
        const float s = (mem > kTHR) ? 1.f : 0.f;
        buf[off] = s;
        dup[off] = s;
    }
}

// ---------------------------------------------------------------------------
extern "C" void kernel_launch(void* const* d_in, const int* in_sizes, int n_in,
                              void* d_out, int out_size, void* d_ws, size_t ws_size,
                              hipStream_t stream) {
    const float* x  = (const float*)d_in[0];   // [100, 512, 700]
    const float* W1 = (const float*)d_in[1];   // [512, 700]
    const float* W2 = (const float*)d_in[2];   // [20, 512]
    float* out = (float*)d_out;

    float* s2a = out + OFF_S2A;   // [T,B,20]  (pre2 then s2)
    float* s1  = out + OFF_S1;    // [T,B,512] (pre1 then s1)
    float* s2b = out + OFF_S2B;   // [T,B,20]  duplicate s2

    // 1) pre1 = x @ W1^T  -> s1 slot  (gll staging, row-major swizzled LDS)
    gemm1_kernel<<<(M_ROWS / BM) * (D1 / BN), 256, 0, stream>>>(x, W1, s1);

    // 2) scan layer 1 in place (pre1 -> spikes)
    scan1_kernel<<<(BATCH * D1) / 256, 256, 0, stream>>>(s1);

    // 3) pre2 = s1 @ W2^T -> s2a slot
    gemm2_kernel<<<M_ROWS / 64, 256, 0, stream>>>(s1, W2, s2a);

    // 4) scan layer 2 in place + duplicate
    scan2_kernel<<<(BATCH * D2) / 256, 256, 0, stream>>>(s2a, s2b);
}